// Round 1
// baseline (211.468 us; speedup 1.0000x reference)
//
#include <hip/hip_runtime.h>
#include <hip/hip_bf16.h>

#define TSEQ 2048
#define BATCH 8
#define NHEAD 4
#define BH (BATCH*NHEAD)
#define HD 32
#define SCALE 0.17677669529663687f   /* 1/sqrt(32) */
#define LAMBDA_INIT 0.8f
#define LN_EPS 1e-5f
#define WIN 256
#define KB 32

typedef __attribute__((ext_vector_type(8))) short short8;
typedef __attribute__((ext_vector_type(4))) float f32x4;

static __device__ __forceinline__ unsigned short f2bf(float x) {
    unsigned int u = __float_as_uint(x);
    unsigned int r = (u + 0x7fffu + ((u >> 16) & 1u)) >> 16;
    return (unsigned short)r;
}

// ---------------- Kernel A: LayerNorm + QKV projection ----------------
// 16 rows per block, 256 threads. Outputs Q,K as [BH][T][64] bf16,
// V transposed as [BH][64][T] bf16 (so attn B-frag reads are contiguous).
__global__ __launch_bounds__(256) void k_qkv(
    const float* __restrict__ tokens, const float* __restrict__ ln_w,
    const float* __restrict__ ln_b,
    const float* __restrict__ wq, const float* __restrict__ wk,
    const float* __restrict__ wv,
    unsigned short* __restrict__ Qg, unsigned short* __restrict__ Kg,
    unsigned short* __restrict__ Vtg)
{
    __shared__ float xl[16][136];
    const int tid = threadIdx.x;
    const int r0 = blockIdx.x * 16;

    // LayerNorm: 16 threads/row, 8 elems each
    {
        const int row = tid >> 4;
        const int sub = tid & 15;
        const float* tr = tokens + (size_t)(r0 + row) * 128 + sub * 8;
        float v[8];
        float s = 0.f, sq = 0.f;
        #pragma unroll
        for (int j = 0; j < 8; j++) { v[j] = tr[j]; s += v[j]; sq += v[j] * v[j]; }
        #pragma unroll
        for (int m = 1; m < 16; m <<= 1) { s += __shfl_xor(s, m, 64); sq += __shfl_xor(sq, m, 64); }
        float mean = s * (1.f / 128.f);
        float var  = sq * (1.f / 128.f) - mean * mean;
        float rstd = rsqrtf(var + LN_EPS);
        #pragma unroll
        for (int j = 0; j < 8; j++) {
            int c = sub * 8 + j;
            xl[row][c] = (v[j] - mean) * rstd * ln_w[c] + ln_b[c];
        }
    }
    __syncthreads();

    // Each thread computes column `tid` of wq/wk/wv for all 16 rows
    float aq[16], ak[16], av[16];
    #pragma unroll
    for (int r = 0; r < 16; r++) { aq[r] = 0.f; ak[r] = 0.f; av[r] = 0.f; }

    for (int i = 0; i < 128; i += 4) {
        float wq_[4], wk_[4], wv_[4];
        #pragma unroll
        for (int j = 0; j < 4; j++) {
            wq_[j] = wq[(i + j) * 256 + tid];
            wk_[j] = wk[(i + j) * 256 + tid];
            wv_[j] = wv[(i + j) * 256 + tid];
        }
        #pragma unroll
        for (int r = 0; r < 16; r++) {
            float4 x = *(const float4*)&xl[r][i];
            aq[r] += x.x * wq_[0] + x.y * wq_[1] + x.z * wq_[2] + x.w * wq_[3];
            ak[r] += x.x * wk_[0] + x.y * wk_[1] + x.z * wk_[2] + x.w * wk_[3];
            av[r] += x.x * wv_[0] + x.y * wv_[1] + x.z * wv_[2] + x.w * wv_[3];
        }
    }

    const int h = tid >> 6, d = tid & 63;
    #pragma unroll
    for (int r = 0; r < 16; r++) {
        int trow = r0 + r;
        int b = trow >> 11;        // /2048
        int t = trow & 2047;
        size_t bhh = (size_t)(b * NHEAD + h);
        size_t qi = (bhh * TSEQ + t) * 64 + d;
        Qg[qi] = f2bf(aq[r]);
        Kg[qi] = f2bf(ak[r]);
        Vtg[(bhh * 64 + d) * TSEQ + t] = f2bf(av[r]);
    }
}

// ---------------- Kernel B: banded differential flash attention --------
// Block: 64 q rows (4 waves x 16), grid (T/64, BH). KB=32 kv per iter.
__global__ __launch_bounds__(256) void k_attn(
    const unsigned short* __restrict__ Qg, const unsigned short* __restrict__ Kg,
    const unsigned short* __restrict__ Vtg,
    const float* __restrict__ lq1, const float* __restrict__ lk1,
    const float* __restrict__ lq2, const float* __restrict__ lk2,
    const float* __restrict__ sig_s_p, const float* __restrict__ sig_n_p,
    const float* __restrict__ hn_w, const float* __restrict__ hn_b,
    float* __restrict__ attn_out)
{
    __shared__ unsigned short k_lds[KB][72];       // [k][64+pad]
    __shared__ unsigned short v_lds[64][40];       // [d][KB+pad] (transposed V)
    __shared__ unsigned short p_lds[4][2][16][40]; // [wave][P1/P2][q][KB+pad]

    const int tid  = threadIdx.x;
    const int wave = tid >> 6;
    const int lane = tid & 63;
    const int lg   = lane >> 4;   // 0..3
    const int li   = lane & 15;   // 0..15

    const int q0 = blockIdx.x * 64;
    const int bh = blockIdx.y;
    const int qw = q0 + wave * 16;

    // lambda scalar (uniform)
    float d1 = 0.f, d2 = 0.f;
    for (int i = 0; i < HD; i++) { d1 += lq1[i] * lk1[i]; d2 += lq2[i] * lk2[i]; }
    const float lam = __expf(d1) - __expf(d2) + LAMBDA_INIT;
    const float inv_ss = 1.f / fmaxf(sig_s_p[0], 1.f);
    const float inv_sn = 1.f / fmaxf(sig_n_p[0], 1.f);

    // Q fragments (A-frag: row = li, k = lg*8+j)
    const unsigned short* qp = Qg + ((size_t)bh * TSEQ + (qw + li)) * 64;
    const short8 q1 = *(const short8*)(qp + lg * 8);
    const short8 q2 = *(const short8*)(qp + 32 + lg * 8);

    f32x4 acc1[4] = {}, acc2[4] = {};
    float m1[4], l1[4], m2[4], l2[4];
    #pragma unroll
    for (int r = 0; r < 4; r++) { m1[r] = -INFINITY; m2[r] = -INFINITY; l1[r] = 0.f; l2[r] = 0.f; }

    // band limits (uniform per block)
    int lo = q0 - WIN; if (lo < 0) lo = 0; lo = (lo / KB) * KB;
    int hi = q0 + 64 + WIN + KB; if (hi > TSEQ) hi = TSEQ;

    const f32x4 zero4 = {0.f, 0.f, 0.f, 0.f};

    for (int kv0 = lo; kv0 < hi; kv0 += KB) {
        __syncthreads();
        // stage K tile (32x64) and Vt tile (64x32)
        {
            int r = tid >> 3, c = (tid & 7) * 8;
            *(short8*)&k_lds[r][c] =
                *(const short8*)(Kg + ((size_t)bh * TSEQ + kv0 + r) * 64 + c);
            int dr = tid >> 2, kc = (tid & 3) * 8;
            *(short8*)&v_lds[dr][kc] =
                *(const short8*)(Vtg + ((size_t)bh * 64 + dr) * TSEQ + kv0 + kc);
        }
        __syncthreads();

        // scores: S = Q K^T  (two 16-col tiles)
        f32x4 s1[2], s2[2];
        #pragma unroll
        for (int t = 0; t < 2; t++) {
            short8 kf1 = *(const short8*)&k_lds[t * 16 + li][lg * 8];
            short8 kf2 = *(const short8*)&k_lds[t * 16 + li][32 + lg * 8];
            s1[t] = __builtin_amdgcn_mfma_f32_16x16x32_bf16(q1, kf1, zero4, 0, 0, 0);
            s2[t] = __builtin_amdgcn_mfma_f32_16x16x32_bf16(q2, kf2, zero4, 0, 0, 0);
        }

        // scale + Gaussian positional bias; online softmax
        float p1[2][4], p2[2][4];
        const int qrb = qw + lg * 4;
        #pragma unroll
        for (int t = 0; t < 2; t++) {
            int kcol = kv0 + t * 16 + li;
            #pragma unroll
            for (int r = 0; r < 4; r++) {
                float rel = (float)(kcol - (qrb + r));
                float b1 = rel * inv_ss; b1 = -0.5f * b1 * b1;
                float b2 = rel * inv_sn; b2 = -0.5f * b2 * b2;
                p1[t][r] = s1[t][r] * SCALE + b1;
                p2[t][r] = s2[t][r] * SCALE + b2;
            }
        }
        #pragma unroll
        for (int r = 0; r < 4; r++) {
            float a1 = fmaxf(p1[0][r], p1[1][r]);
            float a2 = fmaxf(p2[0][r], p2[1][r]);
            #pragma unroll
            for (int m = 1; m < 16; m <<= 1) {
                a1 = fmaxf(a1, __shfl_xor(a1, m, 64));
                a2 = fmaxf(a2, __shfl_xor(a2, m, 64));
            }
            float nm1 = fmaxf(m1[r], a1);
            float nm2 = fmaxf(m2[r], a2);
            float c1 = __expf(m1[r] - nm1);
            float c2 = __expf(m2[r] - nm2);
            m1[r] = nm1; m2[r] = nm2;
            float sum1 = 0.f, sum2 = 0.f;
            #pragma unroll
            for (int t = 0; t < 2; t++) {
                p1[t][r] = __expf(p1[t][r] - nm1);
                p2[t][r] = __expf(p2[t][r] - nm2);
                sum1 += p1[t][r]; sum2 += p2[t][r];
            }
            #pragma unroll
            for (int m = 1; m < 16; m <<= 1) {
                sum1 += __shfl_xor(sum1, m, 64);
                sum2 += __shfl_xor(sum2, m, 64);
            }
            l1[r] = l1[r] * c1 + sum1;
            l2[r] = l2[r] * c2 + sum2;
            #pragma unroll
            for (int t = 0; t < 4; t++) { acc1[t][r] *= c1; acc2[t][r] *= c2; }
        }

        // P (D-layout) -> LDS -> A-frag layout
        #pragma unroll
        for (int t = 0; t < 2; t++) {
            #pragma unroll
            for (int r = 0; r < 4; r++) {
                p_lds[wave][0][lg * 4 + r][t * 16 + li] = f2bf(p1[t][r]);
                p_lds[wave][1][lg * 4 + r][t * 16 + li] = f2bf(p2[t][r]);
            }
        }
        __syncthreads();

        short8 pa1 = *(const short8*)&p_lds[wave][0][li][lg * 8];
        short8 pa2 = *(const short8*)&p_lds[wave][1][li][lg * 8];
        #pragma unroll
        for (int t = 0; t < 4; t++) {
            short8 vf = *(const short8*)&v_lds[t * 16 + li][lg * 8];
            acc1[t] = __builtin_amdgcn_mfma_f32_16x16x32_bf16(pa1, vf, acc1[t], 0, 0, 0);
            acc2[t] = __builtin_amdgcn_mfma_f32_16x16x32_bf16(pa2, vf, acc2[t], 0, 0, 0);
        }
    }

    // epilogue: combine, head-LN over 64, *0.2, store [B][T][H*64]
    float hw[4], hb[4];
    #pragma unroll
    for (int t = 0; t < 4; t++) { hw[t] = hn_w[t * 16 + li]; hb[t] = hn_b[t * 16 + li]; }

    const int b = bh >> 2, h = bh & 3;
    #pragma unroll
    for (int r = 0; r < 4; r++) {
        float il1 = 1.f / l1[r];
        float il2 = lam / l2[r];
        float o[4];
        float s = 0.f, sq = 0.f;
        #pragma unroll
        for (int t = 0; t < 4; t++) {
            o[t] = acc1[t][r] * il1 - acc2[t][r] * il2;
            s += o[t]; sq += o[t] * o[t];
        }
        #pragma unroll
        for (int m = 1; m < 16; m <<= 1) { s += __shfl_xor(s, m, 64); sq += __shfl_xor(sq, m, 64); }
        float mean = s * (1.f / 64.f);
        float var  = sq * (1.f / 64.f) - mean * mean;
        float rstd = rsqrtf(var + LN_EPS);
        int qrow = qw + lg * 4 + r;
        float* op = attn_out + ((size_t)b * TSEQ + qrow) * 256 + h * 64;
        #pragma unroll
        for (int t = 0; t < 4; t++) {
            op[t * 16 + li] = ((o[t] - mean) * rstd * hw[t] + hb[t]) * 0.2f;
        }
    }
}

// ---------------- Kernel C: output projection + residual ----------------
__global__ __launch_bounds__(256) void k_out(
    const float* __restrict__ attn_out, const float* __restrict__ wo,
    const float* __restrict__ tokens, float* __restrict__ out)
{
    __shared__ float al[8][260];
    const int tid = threadIdx.x;
    const int r0 = blockIdx.x * 8;
    {
        int r = tid >> 5;
        int c = (tid & 31) * 8;
        const float* src = attn_out + (size_t)(r0 + r) * 256 + c;
        #pragma unroll
        for (int j = 0; j < 8; j++) al[r][c + j] = src[j];
    }
    __syncthreads();

    const int c  = tid & 127;
    const int rg = tid >> 7;
    float acc[4] = {0.f, 0.f, 0.f, 0.f};
    const float* wop = wo + c;
    for (int i = 0; i < 256; i += 4) {
        float w0 = wop[(i + 0) * 128];
        float w1 = wop[(i + 1) * 128];
        float w2 = wop[(i + 2) * 128];
        float w3 = wop[(i + 3) * 128];
        #pragma unroll
        for (int r = 0; r < 4; r++) {
            float4 a = *(const float4*)&al[rg * 4 + r][i];
            acc[r] += a.x * w0 + a.y * w1 + a.z * w2 + a.w * w3;
        }
    }
    #pragma unroll
    for (int r = 0; r < 4; r++) {
        size_t idx = (size_t)(r0 + rg * 4 + r) * 128 + c;
        out[idx] = tokens[idx] + acc[r];
    }
}

extern "C" void kernel_launch(void* const* d_in, const int* in_sizes, int n_in,
                              void* d_out, int out_size, void* d_ws, size_t ws_size,
                              hipStream_t stream) {
    const float* tokens = (const float*)d_in[0];
    const float* ln_w   = (const float*)d_in[1];
    const float* ln_b   = (const float*)d_in[2];
    const float* wq     = (const float*)d_in[3];
    const float* wk     = (const float*)d_in[4];
    const float* wv     = (const float*)d_in[5];
    const float* wo     = (const float*)d_in[6];
    const float* lq1    = (const float*)d_in[7];
    const float* lk1    = (const float*)d_in[8];
    const float* lq2    = (const float*)d_in[9];
    const float* lk2    = (const float*)d_in[10];
    const float* sigs   = (const float*)d_in[11];
    const float* sign   = (const float*)d_in[12];
    const float* hn_w   = (const float*)d_in[13];
    const float* hn_b   = (const float*)d_in[14];

    const size_t n_qk = (size_t)BH * TSEQ * 64;         // 4.19M bf16 elems each
    unsigned short* Qg  = (unsigned short*)d_ws;
    unsigned short* Kg  = Qg + n_qk;
    unsigned short* Vtg = Kg + n_qk;
    float* attn_out = (float*)(Vtg + n_qk);             // 16384 x 256 fp32

    k_qkv<<<dim3(BATCH * TSEQ / 16), dim3(256), 0, stream>>>(
        tokens, ln_w, ln_b, wq, wk, wv, Qg, Kg, Vtg);
    k_attn<<<dim3(TSEQ / 64, BH), dim3(256), 0, stream>>>(
        Qg, Kg, Vtg, lq1, lk1, lq2, lk2, sigs, sign, hn_w, hn_b, attn_out);
    k_out<<<dim3(BATCH * TSEQ / 8), dim3(256), 0, stream>>>(
        attn_out, wo, tokens, d_out ? (float*)d_out : nullptr);
}

// Round 2
// 163.086 us; speedup vs baseline: 1.2967x; 1.2967x over previous
//
#include <hip/hip_runtime.h>
#include <hip/hip_bf16.h>

#define TSEQ 2048
#define BATCH 8
#define NHEAD 4
#define BH (BATCH*NHEAD)
#define HD 32
#define SCALE 0.17677669529663687f   /* 1/sqrt(32) */
#define LAMBDA_INIT 0.8f
#define LN_EPS 1e-5f

typedef __attribute__((ext_vector_type(8))) short short8;
typedef __attribute__((ext_vector_type(4))) float f32x4;

static __device__ __forceinline__ unsigned short f2bf(float x) {
    unsigned int u = __float_as_uint(x);
    unsigned int r = (u + 0x7fffu + ((u >> 16) & 1u)) >> 16;
    return (unsigned short)r;
}

// ---------------- Kernel A: LayerNorm + QKV projection ----------------
// 16 rows per block, 256 threads. Outputs Q,K as [BH][T][64] bf16,
// V transposed as [BH][64][T] bf16 (so attn B-frag reads are contiguous).
__global__ __launch_bounds__(256) void k_qkv(
    const float* __restrict__ tokens, const float* __restrict__ ln_w,
    const float* __restrict__ ln_b,
    const float* __restrict__ wq, const float* __restrict__ wk,
    const float* __restrict__ wv,
    unsigned short* __restrict__ Qg, unsigned short* __restrict__ Kg,
    unsigned short* __restrict__ Vtg)
{
    __shared__ float xl[16][136];
    const int tid = threadIdx.x;
    const int r0 = blockIdx.x * 16;

    // LayerNorm: 16 threads/row, 8 elems each
    {
        const int row = tid >> 4;
        const int sub = tid & 15;
        const float* tr = tokens + (size_t)(r0 + row) * 128 + sub * 8;
        float v[8];
        float s = 0.f, sq = 0.f;
        #pragma unroll
        for (int j = 0; j < 8; j++) { v[j] = tr[j]; s += v[j]; sq += v[j] * v[j]; }
        #pragma unroll
        for (int m = 1; m < 16; m <<= 1) { s += __shfl_xor(s, m, 64); sq += __shfl_xor(sq, m, 64); }
        float mean = s * (1.f / 128.f);
        float var  = sq * (1.f / 128.f) - mean * mean;
        float rstd = rsqrtf(var + LN_EPS);
        #pragma unroll
        for (int j = 0; j < 8; j++) {
            int c = sub * 8 + j;
            xl[row][c] = (v[j] - mean) * rstd * ln_w[c] + ln_b[c];
        }
    }
    __syncthreads();

    // Each thread computes column `tid` of wq/wk/wv for all 16 rows
    float aq[16], ak[16], av[16];
    #pragma unroll
    for (int r = 0; r < 16; r++) { aq[r] = 0.f; ak[r] = 0.f; av[r] = 0.f; }

    for (int i = 0; i < 128; i += 4) {
        float wq_[4], wk_[4], wv_[4];
        #pragma unroll
        for (int j = 0; j < 4; j++) {
            wq_[j] = wq[(i + j) * 256 + tid];
            wk_[j] = wk[(i + j) * 256 + tid];
            wv_[j] = wv[(i + j) * 256 + tid];
        }
        #pragma unroll
        for (int r = 0; r < 16; r++) {
            float4 x = *(const float4*)&xl[r][i];
            aq[r] += x.x * wq_[0] + x.y * wq_[1] + x.z * wq_[2] + x.w * wq_[3];
            ak[r] += x.x * wk_[0] + x.y * wk_[1] + x.z * wk_[2] + x.w * wk_[3];
            av[r] += x.x * wv_[0] + x.y * wv_[1] + x.z * wv_[2] + x.w * wv_[3];
        }
    }

    const int h = tid >> 6, d = tid & 63;
    const int b = r0 >> 11;        // block fully inside one batch (2048 % 16 == 0)
    const int t0 = r0 & 2047;
    const size_t bhh = (size_t)(b * NHEAD + h);

    #pragma unroll
    for (int r = 0; r < 16; r++) {
        size_t qi = (bhh * TSEQ + t0 + r) * 64 + d;
        Qg[qi] = f2bf(aq[r]);
        Kg[qi] = f2bf(ak[r]);
    }
    // V: this thread owns one (h,d) column; 16 consecutive t values -> 2x16B stores
    {
        short8 v0, v1;
        #pragma unroll
        for (int r = 0; r < 8; r++) { v0[r] = (short)f2bf(av[r]); v1[r] = (short)f2bf(av[8 + r]); }
        unsigned short* vp = Vtg + (bhh * 64 + d) * TSEQ + t0;
        *(short8*)vp = v0;
        *(short8*)(vp + 8) = v1;
    }
}

// ---------------- Kernel B: banded differential attention, 1 wave/block ----
// Wave owns 16 q rows. No barriers, no K/V staging: fragments direct from
// global (L1/L2 reuse). No online max: p = exp(s*SCALE + bias) directly,
// per-lane partial row sums, single reduce at the end.
__global__ __launch_bounds__(64) void k_attn(
    const unsigned short* __restrict__ Qg, const unsigned short* __restrict__ Kg,
    const unsigned short* __restrict__ Vtg,
    const float* __restrict__ lq1, const float* __restrict__ lk1,
    const float* __restrict__ lq2, const float* __restrict__ lk2,
    const float* __restrict__ sig_s_p, const float* __restrict__ sig_n_p,
    const float* __restrict__ hn_w, const float* __restrict__ hn_b,
    float* __restrict__ attn_out)
{
    __shared__ unsigned short p_lds[2][16][36];   // [state][q][k] stride 36 -> conflict-free b16 writes

    const int lane = threadIdx.x;
    const int lg   = lane >> 4;   // 0..3
    const int li   = lane & 15;   // 0..15

    const int qw = blockIdx.x * 16;
    const int bh = blockIdx.y;

    // uniform scalars
    float d1 = 0.f, d2 = 0.f;
    for (int i = 0; i < HD; i++) { d1 += lq1[i] * lk1[i]; d2 += lq2[i] * lk2[i]; }
    const float lam = __expf(d1) - __expf(d2) + LAMBDA_INIT;
    const float ss = fmaxf(sig_s_p[0], 1.f);
    const float sn = fmaxf(sig_n_p[0], 1.f);
    const float c1 = -0.5f / (ss * ss);
    const float c2 = -0.5f / (sn * sn);

    // band width from runtime sigma: tail weight <= e^(ds - W^2/(2 s^2)),
    // W = 10*sigma_max -> e^(16-50) ~ 2e-15, invisible at fp32/bf16.
    int W = (int)ceilf(fmaxf(ss, sn) * 10.f);
    W = (W + 31) & ~31;
    if (W < 64) W = 64;
    int lo = qw - W; if (lo < 0) lo = 0; lo &= ~31;
    int hi = qw + 16 + W; hi = (hi + 31) & ~31; if (hi > TSEQ) hi = TSEQ;

    // Q fragments (A-frag: row=li, k=lg*8+j)
    const unsigned short* qp = Qg + ((size_t)bh * TSEQ + (qw + li)) * 64;
    const short8 q1 = *(const short8*)(qp + lg * 8);
    const short8 q2 = *(const short8*)(qp + 32 + lg * 8);

    // fragment base pointers
    const unsigned short* kbase = Kg  + ((size_t)bh * TSEQ + li) * 64 + lg * 8;
    const unsigned short* vbase = Vtg + ((size_t)bh * 64 + li) * TSEQ + lg * 8;

    f32x4 acc1[4] = {}, acc2[4] = {};
    float ls1[4] = {0.f, 0.f, 0.f, 0.f}, ls2[4] = {0.f, 0.f, 0.f, 0.f};
    const f32x4 zero4 = {0.f, 0.f, 0.f, 0.f};

    for (int kv = lo; kv < hi; kv += 32) {
        // K fragments direct from global: row kv+16t+li, cols lg*8 (+32 for state2)
        const unsigned short* kp = kbase + (size_t)kv * 64;
        short8 kf10 = *(const short8*)(kp);
        short8 kf20 = *(const short8*)(kp + 32);
        short8 kf11 = *(const short8*)(kp + 1024);        // +16 rows * 64
        short8 kf21 = *(const short8*)(kp + 1024 + 32);

        f32x4 s1[2], s2[2];
        s1[0] = __builtin_amdgcn_mfma_f32_16x16x32_bf16(q1, kf10, zero4, 0, 0, 0);
        s1[1] = __builtin_amdgcn_mfma_f32_16x16x32_bf16(q1, kf11, zero4, 0, 0, 0);
        s2[0] = __builtin_amdgcn_mfma_f32_16x16x32_bf16(q2, kf20, zero4, 0, 0, 0);
        s2[1] = __builtin_amdgcn_mfma_f32_16x16x32_bf16(q2, kf21, zero4, 0, 0, 0);

        // p = exp(s*SCALE + c*rel^2); accumulate per-lane row-sum partials
        const float rb = (float)(kv + li - qw - 4 * lg);
        float p1v[2][4], p2v[2][4];
        #pragma unroll
        for (int t = 0; t < 2; t++) {
            #pragma unroll
            for (int r = 0; r < 4; r++) {
                float rel = rb + (float)(16 * t - r);
                float rr  = rel * rel;
                float a1  = fmaf(s1[t][r], SCALE, c1 * rr);
                float a2  = fmaf(s2[t][r], SCALE, c2 * rr);
                float e1  = __expf(a1);
                float e2  = __expf(a2);
                p1v[t][r] = e1; ls1[r] += e1;
                p2v[t][r] = e2; ls2[r] += e2;
            }
        }

        // P (D-layout) -> wave-private LDS -> A-frag layout (no barrier needed)
        #pragma unroll
        for (int t = 0; t < 2; t++) {
            #pragma unroll
            for (int r = 0; r < 4; r++) {
                p_lds[0][lg * 4 + r][t * 16 + li] = f2bf(p1v[t][r]);
                p_lds[1][lg * 4 + r][t * 16 + li] = f2bf(p2v[t][r]);
            }
        }
        short8 pa1 = *(const short8*)&p_lds[0][li][lg * 8];
        short8 pa2 = *(const short8*)&p_lds[1][li][lg * 8];

        // V fragments direct from global: Vt[d = 16t+li][kv + lg*8 + j]
        const unsigned short* vp = vbase + kv;
        #pragma unroll
        for (int t = 0; t < 4; t++) {
            short8 vf = *(const short8*)(vp + (size_t)t * 16 * TSEQ);
            acc1[t] = __builtin_amdgcn_mfma_f32_16x16x32_bf16(pa1, vf, acc1[t], 0, 0, 0);
            acc2[t] = __builtin_amdgcn_mfma_f32_16x16x32_bf16(pa2, vf, acc2[t], 0, 0, 0);
        }
    }

    // reduce row sums across the 16 lanes holding each row's columns
    #pragma unroll
    for (int r = 0; r < 4; r++) {
        #pragma unroll
        for (int m = 1; m < 16; m <<= 1) {
            ls1[r] += __shfl_xor(ls1[r], m, 64);
            ls2[r] += __shfl_xor(ls2[r], m, 64);
        }
    }

    // epilogue: combine, head-LN over 64, *0.2, store [B][T][H*64]
    float hw[4], hb[4];
    #pragma unroll
    for (int t = 0; t < 4; t++) { hw[t] = hn_w[t * 16 + li]; hb[t] = hn_b[t * 16 + li]; }

    const int b = bh >> 2, h = bh & 3;
    #pragma unroll
    for (int r = 0; r < 4; r++) {
        float il1 = 1.f / ls1[r];
        float il2 = lam / ls2[r];
        float o[4];
        float s = 0.f, sq = 0.f;
        #pragma unroll
        for (int t = 0; t < 4; t++) {
            o[t] = acc1[t][r] * il1 - acc2[t][r] * il2;
            s += o[t]; sq += o[t] * o[t];
        }
        #pragma unroll
        for (int m = 1; m < 16; m <<= 1) { s += __shfl_xor(s, m, 64); sq += __shfl_xor(sq, m, 64); }
        float mean = s * (1.f / 64.f);
        float var  = sq * (1.f / 64.f) - mean * mean;
        float rstd = rsqrtf(var + LN_EPS);
        int qrow = qw + lg * 4 + r;
        float* op = attn_out + ((size_t)b * TSEQ + qrow) * 256 + h * 64;
        #pragma unroll
        for (int t = 0; t < 4; t++) {
            op[t * 16 + li] = ((o[t] - mean) * rstd * hw[t] + hb[t]) * 0.2f;
        }
    }
}

// ---------------- Kernel C: output projection + residual ----------------
__global__ __launch_bounds__(256) void k_out(
    const float* __restrict__ attn_out, const float* __restrict__ wo,
    const float* __restrict__ tokens, float* __restrict__ out)
{
    __shared__ float al[8][260];
    const int tid = threadIdx.x;
    const int r0 = blockIdx.x * 8;
    {
        int r = tid >> 5;
        int c = (tid & 31) * 8;
        const float* src = attn_out + (size_t)(r0 + r) * 256 + c;
        #pragma unroll
        for (int j = 0; j < 8; j++) al[r][c + j] = src[j];
    }
    __syncthreads();

    const int c  = tid & 127;
    const int rg = tid >> 7;
    float acc[4] = {0.f, 0.f, 0.f, 0.f};
    const float* wop = wo + c;
    for (int i = 0; i < 256; i += 4) {
        float w0 = wop[(i + 0) * 128];
        float w1 = wop[(i + 1) * 128];
        float w2 = wop[(i + 2) * 128];
        float w3 = wop[(i + 3) * 128];
        #pragma unroll
        for (int r = 0; r < 4; r++) {
            float4 a = *(const float4*)&al[rg * 4 + r][i];
            acc[r] += a.x * w0 + a.y * w1 + a.z * w2 + a.w * w3;
        }
    }
    #pragma unroll
    for (int r = 0; r < 4; r++) {
        size_t idx = (size_t)(r0 + rg * 4 + r) * 128 + c;
        out[idx] = tokens[idx] + acc[r];
    }
}

extern "C" void kernel_launch(void* const* d_in, const int* in_sizes, int n_in,
                              void* d_out, int out_size, void* d_ws, size_t ws_size,
                              hipStream_t stream) {
    const float* tokens = (const float*)d_in[0];
    const float* ln_w   = (const float*)d_in[1];
    const float* ln_b   = (const float*)d_in[2];
    const float* wq     = (const float*)d_in[3];
    const float* wk     = (const float*)d_in[4];
    const float* wv     = (const float*)d_in[5];
    const float* wo     = (const float*)d_in[6];
    const float* lq1    = (const float*)d_in[7];
    const float* lk1    = (const float*)d_in[8];
    const float* lq2    = (const float*)d_in[9];
    const float* lk2    = (const float*)d_in[10];
    const float* sigs   = (const float*)d_in[11];
    const float* sign   = (const float*)d_in[12];
    const float* hn_w   = (const float*)d_in[13];
    const float* hn_b   = (const float*)d_in[14];

    const size_t n_qk = (size_t)BH * TSEQ * 64;
    unsigned short* Qg  = (unsigned short*)d_ws;
    unsigned short* Kg  = Qg + n_qk;
    unsigned short* Vtg = Kg + n_qk;
    float* attn_out = (float*)(Vtg + n_qk);             // 16384 x 256 fp32

    k_qkv<<<dim3(BATCH * TSEQ / 16), dim3(256), 0, stream>>>(
        tokens, ln_w, ln_b, wq, wk, wv, Qg, Kg, Vtg);
    k_attn<<<dim3(TSEQ / 16, BH), dim3(64), 0, stream>>>(
        Qg, Kg, Vtg, lq1, lk1, lq2, lk2, sigs, sign, hn_w, hn_b, attn_out);
    k_out<<<dim3(BATCH * TSEQ / 8), dim3(256), 0, stream>>>(
        attn_out, wo, tokens, d_out ? (float*)d_out : nullptr);
}

// Round 3
// 117.960 us; speedup vs baseline: 1.7927x; 1.3826x over previous
//
#include <hip/hip_runtime.h>
#include <hip/hip_bf16.h>

#define TSEQ 2048
#define BATCH 8
#define NHEAD 4
#define BH (BATCH*NHEAD)
#define HD 32
#define SCALE 0.17677669529663687f   /* 1/sqrt(32) */
#define LAMBDA_INIT 0.8f
#define LN_EPS 1e-5f

typedef __attribute__((ext_vector_type(8))) short short8;
typedef __attribute__((ext_vector_type(4))) float f32x4;

static __device__ __forceinline__ unsigned short f2bf(float x) {
    unsigned int u = __float_as_uint(x);
    unsigned int r = (u + 0x7fffu + ((u >> 16) & 1u)) >> 16;
    return (unsigned short)r;
}

// ---------------- Kernel P: weight transpose + bf16 cast ----------------
// WqkvT bf16 [768][128]  (rows 0-255 = wq cols, 256-511 = wk, 512-767 = wv)
// WoT   bf16 [128][256]
__global__ __launch_bounds__(256) void k_prep(
    const float* __restrict__ wq, const float* __restrict__ wk,
    const float* __restrict__ wv, const float* __restrict__ wo,
    unsigned short* __restrict__ WqkvT, unsigned short* __restrict__ WoT)
{
    __shared__ float xt[64][65];
    const int bid = blockIdx.x, tid = threadIdx.x;
    const float* src; int srcN, k0, nsrc0, dstK;
    unsigned short* dst;
    if (bid < 24) {
        int ntile = bid >> 1, ktile = bid & 1;
        int gn0 = ntile * 64; k0 = ktile * 64;
        int mat = gn0 >> 8;
        src = (mat == 0) ? wq : (mat == 1 ? wk : wv);
        srcN = 256; nsrc0 = gn0 & 255;
        dst = WqkvT + (size_t)gn0 * 128; dstK = 128;
    } else {
        int b2 = bid - 24;
        int ntile = b2 >> 2, ktile = b2 & 3;
        int gn0 = ntile * 64; k0 = ktile * 64;
        src = wo; srcN = 128; nsrc0 = gn0;
        dst = WoT + (size_t)gn0 * 256; dstK = 256;
    }
    {
        int r = tid >> 2, cs = tid & 3;
        const float* sp = src + (size_t)(k0 + r) * srcN + nsrc0 + cs * 16;
        #pragma unroll
        for (int j = 0; j < 4; j++) {
            float4 v = *(const float4*)(sp + j * 4);
            xt[r][cs * 16 + j * 4 + 0] = v.x;
            xt[r][cs * 16 + j * 4 + 1] = v.y;
            xt[r][cs * 16 + j * 4 + 2] = v.z;
            xt[r][cs * 16 + j * 4 + 3] = v.w;
        }
    }
    __syncthreads();
    {
        int n = tid >> 2, ks = tid & 3;
        short8 o0, o1;
        #pragma unroll
        for (int j = 0; j < 8; j++) {
            o0[j] = (short)f2bf(xt[ks * 16 + j][n]);
            o1[j] = (short)f2bf(xt[ks * 16 + 8 + j][n]);
        }
        unsigned short* dp = dst + (size_t)n * dstK + k0 + ks * 16;
        *(short8*)dp = o0;
        *(short8*)(dp + 8) = o1;
    }
}

// ---------------- Kernel A: LayerNorm + QKV projection (MFMA) ----------
// Block: 32 rows, 256 threads (4 waves). Wave w: row-tile w>>1, col-half w&1
// (384 cols each). Outputs Q,K [BH][T][64] bf16; V transposed [BH][64][T].
__global__ __launch_bounds__(256) void k_qkv(
    const float* __restrict__ tokens, const float* __restrict__ ln_w,
    const float* __restrict__ ln_b, const unsigned short* __restrict__ WqkvT,
    unsigned short* __restrict__ Qg, unsigned short* __restrict__ Kg,
    unsigned short* __restrict__ Vtg)
{
    __shared__ unsigned short x_lds[32][132];
    __shared__ unsigned short c_lds[4][16][68];
    const int tid = threadIdx.x;
    const int r0 = blockIdx.x * 32;

    // LayerNorm: 8 threads/row, 16 elems each -> bf16 in LDS
    {
        int row = tid >> 3, sub = tid & 7;
        const float* tr = tokens + (size_t)(r0 + row) * 128 + sub * 16;
        float v[16]; float s = 0.f, sq = 0.f;
        #pragma unroll
        for (int j = 0; j < 16; j += 4) {
            float4 t4 = *(const float4*)(tr + j);
            v[j] = t4.x; v[j + 1] = t4.y; v[j + 2] = t4.z; v[j + 3] = t4.w;
        }
        #pragma unroll
        for (int j = 0; j < 16; j++) { s += v[j]; sq += v[j] * v[j]; }
        #pragma unroll
        for (int m = 1; m < 8; m <<= 1) { s += __shfl_xor(s, m, 64); sq += __shfl_xor(sq, m, 64); }
        float mean = s * (1.f / 128.f);
        float var  = sq * (1.f / 128.f) - mean * mean;
        float rstd = rsqrtf(var + LN_EPS);
        short8 o0, o1;
        #pragma unroll
        for (int j = 0; j < 8; j++) {
            int c0 = sub * 16 + j, c1 = sub * 16 + 8 + j;
            o0[j] = (short)f2bf((v[j] - mean) * rstd * ln_w[c0] + ln_b[c0]);
            o1[j] = (short)f2bf((v[8 + j] - mean) * rstd * ln_w[c1] + ln_b[c1]);
        }
        *(short8*)&x_lds[row][sub * 16] = o0;
        *(short8*)&x_lds[row][sub * 16 + 8] = o1;
    }
    __syncthreads();

    const int w = tid >> 6, lane = tid & 63;
    const int lg = lane >> 4, li = lane & 15;
    const int rt = w >> 1, ch = w & 1;

    short8 a[4];
    #pragma unroll
    for (int kc = 0; kc < 4; kc++)
        a[kc] = *(const short8*)&x_lds[rt * 16 + li][kc * 32 + lg * 8];

    const int b   = r0 >> 11;
    const int tw0 = (r0 & 2047) + rt * 16;

    #pragma unroll
    for (int cc = 0; cc < 6; cc++) {
        f32x4 acc[4] = {};
        #pragma unroll
        for (int t = 0; t < 4; t++) {
            int n0 = ch * 384 + cc * 64 + t * 16;
            const unsigned short* bp = WqkvT + (size_t)(n0 + li) * 128 + lg * 8;
            #pragma unroll
            for (int kc = 0; kc < 4; kc++) {
                short8 bf = *(const short8*)(bp + kc * 32);
                acc[t] = __builtin_amdgcn_mfma_f32_16x16x32_bf16(a[kc], bf, acc[t], 0, 0, 0);
            }
        }
        // D-frags -> wave-private LDS chunk [16 rows][64 cols]
        #pragma unroll
        for (int t = 0; t < 4; t++)
            #pragma unroll
            for (int r = 0; r < 4; r++)
                c_lds[w][lg * 4 + r][t * 16 + li] = f2bf(acc[t][r]);

        int gc = ch * 6 + cc;
        int kind = gc >> 2, h = gc & 3;
        size_t bhh = (size_t)(b * NHEAD + h);
        if (kind < 2) {
            unsigned short* base = (kind == 0) ? Qg : Kg;
            int row = lane >> 2, seg = lane & 3;
            unsigned short* dp = base + (bhh * TSEQ + tw0 + row) * 64 + seg * 16;
            *(short8*)dp       = *(const short8*)&c_lds[w][row][seg * 16];
            *(short8*)(dp + 8) = *(const short8*)&c_lds[w][row][seg * 16 + 8];
        } else {
            int d = lane;
            short8 v0, v1;
            #pragma unroll
            for (int j = 0; j < 8; j++) {
                v0[j] = (short)c_lds[w][j][d];
                v1[j] = (short)c_lds[w][8 + j][d];
            }
            unsigned short* dp = Vtg + (bhh * 64 + d) * TSEQ + tw0;
            *(short8*)dp = v0;
            *(short8*)(dp + 8) = v1;
        }
    }
}

// ---------------- Kernel B: banded differential attention, 1 wave/block ----
__global__ __launch_bounds__(64) void k_attn(
    const unsigned short* __restrict__ Qg, const unsigned short* __restrict__ Kg,
    const unsigned short* __restrict__ Vtg,
    const float* __restrict__ lq1, const float* __restrict__ lk1,
    const float* __restrict__ lq2, const float* __restrict__ lk2,
    const float* __restrict__ sig_s_p, const float* __restrict__ sig_n_p,
    const float* __restrict__ hn_w, const float* __restrict__ hn_b,
    unsigned short* __restrict__ attn_out)
{
    __shared__ unsigned short p_lds[2][16][36];

    const int lane = threadIdx.x;
    const int lg   = lane >> 4;
    const int li   = lane & 15;

    const int qw = blockIdx.x * 16;
    const int bh = blockIdx.y;

    float d1 = 0.f, d2 = 0.f;
    for (int i = 0; i < HD; i++) { d1 += lq1[i] * lk1[i]; d2 += lq2[i] * lk2[i]; }
    const float lam = __expf(d1) - __expf(d2) + LAMBDA_INIT;
    const float ss = fmaxf(sig_s_p[0], 1.f);
    const float sn = fmaxf(sig_n_p[0], 1.f);
    const float c1 = -0.5f / (ss * ss);
    const float c2 = -0.5f / (sn * sn);

    int W = (int)ceilf(fmaxf(ss, sn) * 10.f);
    W = (W + 31) & ~31;
    if (W < 64) W = 64;
    int lo = qw - W; if (lo < 0) lo = 0; lo &= ~31;
    int hi = qw + 16 + W; hi = (hi + 31) & ~31; if (hi > TSEQ) hi = TSEQ;

    const unsigned short* qp = Qg + ((size_t)bh * TSEQ + (qw + li)) * 64;
    const short8 q1 = *(const short8*)(qp + lg * 8);
    const short8 q2 = *(const short8*)(qp + 32 + lg * 8);

    const unsigned short* kbase = Kg  + ((size_t)bh * TSEQ + li) * 64 + lg * 8;
    const unsigned short* vbase = Vtg + ((size_t)bh * 64 + li) * TSEQ + lg * 8;

    f32x4 acc1[4] = {}, acc2[4] = {};
    float ls1[4] = {0.f, 0.f, 0.f, 0.f}, ls2[4] = {0.f, 0.f, 0.f, 0.f};
    const f32x4 zero4 = {0.f, 0.f, 0.f, 0.f};

    for (int kv = lo; kv < hi; kv += 32) {
        const unsigned short* kp = kbase + (size_t)kv * 64;
        short8 kf10 = *(const short8*)(kp);
        short8 kf20 = *(const short8*)(kp + 32);
        short8 kf11 = *(const short8*)(kp + 1024);
        short8 kf21 = *(const short8*)(kp + 1024 + 32);

        f32x4 s1[2], s2[2];
        s1[0] = __builtin_amdgcn_mfma_f32_16x16x32_bf16(q1, kf10, zero4, 0, 0, 0);
        s1[1] = __builtin_amdgcn_mfma_f32_16x16x32_bf16(q1, kf11, zero4, 0, 0, 0);
        s2[0] = __builtin_amdgcn_mfma_f32_16x16x32_bf16(q2, kf20, zero4, 0, 0, 0);
        s2[1] = __builtin_amdgcn_mfma_f32_16x16x32_bf16(q2, kf21, zero4, 0, 0, 0);

        const float rb = (float)(kv + li - qw - 4 * lg);
        float p1v[2][4], p2v[2][4];
        #pragma unroll
        for (int t = 0; t < 2; t++) {
            #pragma unroll
            for (int r = 0; r < 4; r++) {
                float rel = rb + (float)(16 * t - r);
                float rr  = rel * rel;
                float a1  = fmaf(s1[t][r], SCALE, c1 * rr);
                float a2  = fmaf(s2[t][r], SCALE, c2 * rr);
                float e1  = __expf(a1);
                float e2  = __expf(a2);
                p1v[t][r] = e1; ls1[r] += e1;
                p2v[t][r] = e2; ls2[r] += e2;
            }
        }

        #pragma unroll
        for (int t = 0; t < 2; t++) {
            #pragma unroll
            for (int r = 0; r < 4; r++) {
                p_lds[0][lg * 4 + r][t * 16 + li] = f2bf(p1v[t][r]);
                p_lds[1][lg * 4 + r][t * 16 + li] = f2bf(p2v[t][r]);
            }
        }
        short8 pa1 = *(const short8*)&p_lds[0][li][lg * 8];
        short8 pa2 = *(const short8*)&p_lds[1][li][lg * 8];

        const unsigned short* vp = vbase + kv;
        #pragma unroll
        for (int t = 0; t < 4; t++) {
            short8 vf = *(const short8*)(vp + (size_t)t * 16 * TSEQ);
            acc1[t] = __builtin_amdgcn_mfma_f32_16x16x32_bf16(pa1, vf, acc1[t], 0, 0, 0);
            acc2[t] = __builtin_amdgcn_mfma_f32_16x16x32_bf16(pa2, vf, acc2[t], 0, 0, 0);
        }
    }

    #pragma unroll
    for (int r = 0; r < 4; r++) {
        #pragma unroll
        for (int m = 1; m < 16; m <<= 1) {
            ls1[r] += __shfl_xor(ls1[r], m, 64);
            ls2[r] += __shfl_xor(ls2[r], m, 64);
        }
    }

    float hw[4], hb[4];
    #pragma unroll
    for (int t = 0; t < 4; t++) { hw[t] = hn_w[t * 16 + li]; hb[t] = hn_b[t * 16 + li]; }

    const int b = bh >> 2, h = bh & 3;
    #pragma unroll
    for (int r = 0; r < 4; r++) {
        float il1 = 1.f / ls1[r];
        float il2 = lam / ls2[r];
        float o[4];
        float s = 0.f, sq = 0.f;
        #pragma unroll
        for (int t = 0; t < 4; t++) {
            o[t] = acc1[t][r] * il1 - acc2[t][r] * il2;
            s += o[t]; sq += o[t] * o[t];
        }
        #pragma unroll
        for (int m = 1; m < 16; m <<= 1) { s += __shfl_xor(s, m, 64); sq += __shfl_xor(sq, m, 64); }
        float mean = s * (1.f / 64.f);
        float var  = sq * (1.f / 64.f) - mean * mean;
        float rstd = rsqrtf(var + LN_EPS);
        int qrow = qw + lg * 4 + r;
        unsigned short* op = attn_out + ((size_t)b * TSEQ + qrow) * 256 + h * 64;
        #pragma unroll
        for (int t = 0; t < 4; t++) {
            op[t * 16 + li] = f2bf(((o[t] - mean) * rstd * hw[t] + hb[t]) * 0.2f);
        }
    }
}

// ---------------- Kernel C: output projection + residual (MFMA) --------
// Block: 32 rows, 256 threads. Wave w: row-tile w>>1, col-half w&1 (64 cols).
__global__ __launch_bounds__(256) void k_out(
    const unsigned short* __restrict__ attn_out, const unsigned short* __restrict__ WoT,
    const float* __restrict__ tokens, float* __restrict__ out)
{
    const int tid = threadIdx.x;
    const int w = tid >> 6, lane = tid & 63;
    const int lg = lane >> 4, li = lane & 15;
    const int rt = w >> 1, chh = w & 1;
    const int r0 = blockIdx.x * 32 + rt * 16;

    short8 a[8];
    const unsigned short* ap = attn_out + (size_t)(r0 + li) * 256 + lg * 8;
    #pragma unroll
    for (int kc = 0; kc < 8; kc++) a[kc] = *(const short8*)(ap + kc * 32);

    #pragma unroll
    for (int c2 = 0; c2 < 4; c2++) {
        int ct = chh * 4 + c2;
        f32x4 acc = {};
        const unsigned short* bp = WoT + (size_t)(ct * 16 + li) * 256 + lg * 8;
        #pragma unroll
        for (int kc = 0; kc < 8; kc++) {
            short8 bf = *(const short8*)(bp + kc * 32);
            acc = __builtin_amdgcn_mfma_f32_16x16x32_bf16(a[kc], bf, acc, 0, 0, 0);
        }
        #pragma unroll
        for (int r = 0; r < 4; r++) {
            size_t idx = (size_t)(r0 + lg * 4 + r) * 128 + ct * 16 + li;
            out[idx] = tokens[idx] + acc[r];
        }
    }
}

extern "C" void kernel_launch(void* const* d_in, const int* in_sizes, int n_in,
                              void* d_out, int out_size, void* d_ws, size_t ws_size,
                              hipStream_t stream) {
    const float* tokens = (const float*)d_in[0];
    const float* ln_w   = (const float*)d_in[1];
    const float* ln_b   = (const float*)d_in[2];
    const float* wq     = (const float*)d_in[3];
    const float* wk     = (const float*)d_in[4];
    const float* wv     = (const float*)d_in[5];
    const float* wo     = (const float*)d_in[6];
    const float* lq1    = (const float*)d_in[7];
    const float* lk1    = (const float*)d_in[8];
    const float* lq2    = (const float*)d_in[9];
    const float* lk2    = (const float*)d_in[10];
    const float* sigs   = (const float*)d_in[11];
    const float* sign   = (const float*)d_in[12];
    const float* hn_w   = (const float*)d_in[13];
    const float* hn_b   = (const float*)d_in[14];

    const size_t n_qk = (size_t)BH * TSEQ * 64;   // 4.19M
    unsigned short* Qg      = (unsigned short*)d_ws;
    unsigned short* Kg      = Qg + n_qk;
    unsigned short* Vtg     = Kg + n_qk;
    unsigned short* attn_o  = Vtg + n_qk;         // [16384][256] bf16
    unsigned short* WqkvT   = attn_o + n_qk;      // [768][128]
    unsigned short* WoT     = WqkvT + 768 * 128;  // [128][256]

    k_prep<<<dim3(32), dim3(256), 0, stream>>>(wq, wk, wv, wo, WqkvT, WoT);
    k_qkv<<<dim3(BATCH * TSEQ / 32), dim3(256), 0, stream>>>(
        tokens, ln_w, ln_b, WqkvT, Qg, Kg, Vtg);
    k_attn<<<dim3(TSEQ / 16, BH), dim3(64), 0, stream>>>(
        Qg, Kg, Vtg, lq1, lk1, lq2, lk2, sigs, sign, hn_w, hn_b, attn_o);
    k_out<<<dim3(BATCH * TSEQ / 32), dim3(256), 0, stream>>>(
        attn_o, WoT, tokens, (float*)d_out);
}

// Round 4
// 74.022 us; speedup vs baseline: 2.8568x; 1.5936x over previous
//
#include <hip/hip_runtime.h>
#include <hip/hip_bf16.h>

#define TSEQ 2048
#define BATCH 8
#define NHEAD 4
#define BH (BATCH*NHEAD)
#define HD 32
#define SCALE 0.17677669529663687f   /* 1/sqrt(32) */
#define LAMBDA_INIT 0.8f
#define LN_EPS 1e-5f

typedef __attribute__((ext_vector_type(8))) short short8;
typedef __attribute__((ext_vector_type(4))) float f32x4;

static __device__ __forceinline__ unsigned short f2bf(float x) {
    unsigned int u = __float_as_uint(x);
    unsigned int r = (u + 0x7fffu + ((u >> 16) & 1u)) >> 16;
    return (unsigned short)r;
}

// ---------------- Kernel P: weight transpose + bf16 cast ----------------
__global__ __launch_bounds__(256) void k_prep(
    const float* __restrict__ wq, const float* __restrict__ wk,
    const float* __restrict__ wv, const float* __restrict__ wo,
    unsigned short* __restrict__ WqkvT, unsigned short* __restrict__ WoT)
{
    __shared__ float xt[64][65];
    const int bid = blockIdx.x, tid = threadIdx.x;
    const float* src; int srcN, k0, nsrc0, dstK;
    unsigned short* dst;
    if (bid < 24) {
        int ntile = bid >> 1, ktile = bid & 1;
        int gn0 = ntile * 64; k0 = ktile * 64;
        int mat = gn0 >> 8;
        src = (mat == 0) ? wq : (mat == 1 ? wk : wv);
        srcN = 256; nsrc0 = gn0 & 255;
        dst = WqkvT + (size_t)gn0 * 128; dstK = 128;
    } else {
        int b2 = bid - 24;
        int ntile = b2 >> 2, ktile = b2 & 3;
        int gn0 = ntile * 64; k0 = ktile * 64;
        src = wo; srcN = 128; nsrc0 = gn0;
        dst = WoT + (size_t)gn0 * 256; dstK = 256;
    }
    {
        int r = tid >> 2, cs = tid & 3;
        const float* sp = src + (size_t)(k0 + r) * srcN + nsrc0 + cs * 16;
        #pragma unroll
        for (int j = 0; j < 4; j++) {
            float4 v = *(const float4*)(sp + j * 4);
            xt[r][cs * 16 + j * 4 + 0] = v.x;
            xt[r][cs * 16 + j * 4 + 1] = v.y;
            xt[r][cs * 16 + j * 4 + 2] = v.z;
            xt[r][cs * 16 + j * 4 + 3] = v.w;
        }
    }
    __syncthreads();
    {
        int n = tid >> 2, ks = tid & 3;
        short8 o0, o1;
        #pragma unroll
        for (int j = 0; j < 8; j++) {
            o0[j] = (short)f2bf(xt[ks * 16 + j][n]);
            o1[j] = (short)f2bf(xt[ks * 16 + 8 + j][n]);
        }
        unsigned short* dp = dst + (size_t)n * dstK + k0 + ks * 16;
        *(short8*)dp = o0;
        *(short8*)(dp + 8) = o1;
    }
}

// ---------------- Kernel A: LayerNorm + QKV projection (MFMA) ----------
__global__ __launch_bounds__(256) void k_qkv(
    const float* __restrict__ tokens, const float* __restrict__ ln_w,
    const float* __restrict__ ln_b, const unsigned short* __restrict__ WqkvT,
    unsigned short* __restrict__ Qg, unsigned short* __restrict__ Kg,
    unsigned short* __restrict__ Vtg)
{
    __shared__ unsigned short x_lds[32][132];
    __shared__ unsigned short c_lds[4][16][68];
    const int tid = threadIdx.x;
    const int r0 = blockIdx.x * 32;

    {
        int row = tid >> 3, sub = tid & 7;
        const float* tr = tokens + (size_t)(r0 + row) * 128 + sub * 16;
        float v[16]; float s = 0.f, sq = 0.f;
        #pragma unroll
        for (int j = 0; j < 16; j += 4) {
            float4 t4 = *(const float4*)(tr + j);
            v[j] = t4.x; v[j + 1] = t4.y; v[j + 2] = t4.z; v[j + 3] = t4.w;
        }
        #pragma unroll
        for (int j = 0; j < 16; j++) { s += v[j]; sq += v[j] * v[j]; }
        #pragma unroll
        for (int m = 1; m < 8; m <<= 1) { s += __shfl_xor(s, m, 64); sq += __shfl_xor(sq, m, 64); }
        float mean = s * (1.f / 128.f);
        float var  = sq * (1.f / 128.f) - mean * mean;
        float rstd = rsqrtf(var + LN_EPS);
        short8 o0, o1;
        #pragma unroll
        for (int j = 0; j < 8; j++) {
            int c0 = sub * 16 + j, c1 = sub * 16 + 8 + j;
            o0[j] = (short)f2bf((v[j] - mean) * rstd * ln_w[c0] + ln_b[c0]);
            o1[j] = (short)f2bf((v[8 + j] - mean) * rstd * ln_w[c1] + ln_b[c1]);
        }
        *(short8*)&x_lds[row][sub * 16] = o0;
        *(short8*)&x_lds[row][sub * 16 + 8] = o1;
    }
    __syncthreads();

    const int w = tid >> 6, lane = tid & 63;
    const int lg = lane >> 4, li = lane & 15;
    const int rt = w >> 1, ch = w & 1;

    short8 a[4];
    #pragma unroll
    for (int kc = 0; kc < 4; kc++)
        a[kc] = *(const short8*)&x_lds[rt * 16 + li][kc * 32 + lg * 8];

    const int b   = r0 >> 11;
    const int tw0 = (r0 & 2047) + rt * 16;

    #pragma unroll
    for (int cc = 0; cc < 6; cc++) {
        f32x4 acc[4] = {};
        #pragma unroll
        for (int t = 0; t < 4; t++) {
            int n0 = ch * 384 + cc * 64 + t * 16;
            const unsigned short* bp = WqkvT + (size_t)(n0 + li) * 128 + lg * 8;
            #pragma unroll
            for (int kc = 0; kc < 4; kc++) {
                short8 bf = *(const short8*)(bp + kc * 32);
                acc[t] = __builtin_amdgcn_mfma_f32_16x16x32_bf16(a[kc], bf, acc[t], 0, 0, 0);
            }
        }
        #pragma unroll
        for (int t = 0; t < 4; t++)
            #pragma unroll
            for (int r = 0; r < 4; r++)
                c_lds[w][lg * 4 + r][t * 16 + li] = f2bf(acc[t][r]);

        int gc = ch * 6 + cc;
        int kind = gc >> 2, h = gc & 3;
        size_t bhh = (size_t)(b * NHEAD + h);
        if (kind < 2) {
            unsigned short* base = (kind == 0) ? Qg : Kg;
            int row = lane >> 2, seg = lane & 3;
            unsigned short* dp = base + (bhh * TSEQ + tw0 + row) * 64 + seg * 16;
            *(short8*)dp       = *(const short8*)&c_lds[w][row][seg * 16];
            *(short8*)(dp + 8) = *(const short8*)&c_lds[w][row][seg * 16 + 8];
        } else {
            int d = lane;
            short8 v0, v1;
            #pragma unroll
            for (int j = 0; j < 8; j++) {
                v0[j] = (short)c_lds[w][j][d];
                v1[j] = (short)c_lds[w][8 + j][d];
            }
            unsigned short* dp = Vtg + (bhh * 64 + d) * TSEQ + tw0;
            *(short8*)dp = v0;
            *(short8*)(dp + 8) = v1;
        }
    }
}

// ---------------- Kernel B: banded differential attention ----------------
// 1 wave/block, 32 q rows (two 16-row tiles). XCD-aware mapping: xcd = bid&7
// owns bh planes [xcd*4, xcd*4+4) so each XCD's K/V working set (2 MB) fits
// its private 4 MB L2.
__global__ __launch_bounds__(64) void k_attn(
    const unsigned short* __restrict__ Qg, const unsigned short* __restrict__ Kg,
    const unsigned short* __restrict__ Vtg,
    const float* __restrict__ lq1, const float* __restrict__ lk1,
    const float* __restrict__ lq2, const float* __restrict__ lk2,
    const float* __restrict__ sig_s_p, const float* __restrict__ sig_n_p,
    const float* __restrict__ hn_w, const float* __restrict__ hn_b,
    unsigned short* __restrict__ attn_out)
{
    __shared__ unsigned short p_lds[2][32][36];

    const int lane = threadIdx.x;
    const int lg   = lane >> 4;
    const int li   = lane & 15;

    // XCD-aware block mapping (perf heuristic only)
    const int xcd = blockIdx.x & 7;
    const int idx = blockIdx.x >> 3;
    const int bh  = (xcd << 2) | (idx >> 6);
    const int qw  = (idx & 63) * 32;

    float d1 = 0.f, d2 = 0.f;
    for (int i = 0; i < HD; i++) { d1 += lq1[i] * lk1[i]; d2 += lq2[i] * lk2[i]; }
    const float lam = __expf(d1) - __expf(d2) + LAMBDA_INIT;
    const float ss = fmaxf(sig_s_p[0], 1.f);
    const float sn = fmaxf(sig_n_p[0], 1.f);
    const float c1 = -0.5f / (ss * ss);
    const float c2 = -0.5f / (sn * sn);

    // band: W = 8*sigma_max (tail <= e^-34 relative, invisible)
    int W = (int)ceilf(fmaxf(ss, sn) * 8.f);
    W = (W + 31) & ~31;
    if (W < 64) W = 64;
    int lo = qw - W; if (lo < 0) lo = 0; lo &= ~31;
    int hi = qw + 32 + W; hi = (hi + 31) & ~31; if (hi > TSEQ) hi = TSEQ;

    // Q fragments for both 16-row tiles (A-frag: row=li, k=lg*8+j)
    short8 q1[2], q2[2];
    #pragma unroll
    for (int qt = 0; qt < 2; qt++) {
        const unsigned short* qp = Qg + ((size_t)bh * TSEQ + (qw + qt * 16 + li)) * 64;
        q1[qt] = *(const short8*)(qp + lg * 8);
        q2[qt] = *(const short8*)(qp + 32 + lg * 8);
    }

    const unsigned short* kbase = Kg  + ((size_t)bh * TSEQ + li) * 64 + lg * 8;
    const unsigned short* vbase = Vtg + ((size_t)bh * 64 + li) * TSEQ + lg * 8;

    f32x4 acc1[2][4] = {}, acc2[2][4] = {};
    float ls1[2][4] = {}, ls2[2][4] = {};
    const f32x4 zero4 = {0.f, 0.f, 0.f, 0.f};

    for (int kv = lo; kv < hi; kv += 32) {
        // K fragments: tile kt rows kv+kt*16+li, state s cols s*32+lg*8
        const unsigned short* kp = kbase + (size_t)kv * 64;
        short8 kf1[2], kf2[2];
        kf1[0] = *(const short8*)(kp);
        kf2[0] = *(const short8*)(kp + 32);
        kf1[1] = *(const short8*)(kp + 1024);
        kf2[1] = *(const short8*)(kp + 1024 + 32);

        #pragma unroll
        for (int qt = 0; qt < 2; qt++) {
            f32x4 s1[2], s2[2];
            #pragma unroll
            for (int kt = 0; kt < 2; kt++) {
                s1[kt] = __builtin_amdgcn_mfma_f32_16x16x32_bf16(q1[qt], kf1[kt], zero4, 0, 0, 0);
                s2[kt] = __builtin_amdgcn_mfma_f32_16x16x32_bf16(q2[qt], kf2[kt], zero4, 0, 0, 0);
            }
            const float rb = (float)(kv + li - qw - qt * 16 - 4 * lg);
            #pragma unroll
            for (int kt = 0; kt < 2; kt++) {
                #pragma unroll
                for (int r = 0; r < 4; r++) {
                    float rel = rb + (float)(16 * kt - r);
                    float rr  = rel * rel;
                    float e1  = __expf(fmaf(s1[kt][r], SCALE, c1 * rr));
                    float e2  = __expf(fmaf(s2[kt][r], SCALE, c2 * rr));
                    ls1[qt][r] += e1;
                    ls2[qt][r] += e2;
                    p_lds[0][qt * 16 + lg * 4 + r][kt * 16 + li] = f2bf(e1);
                    p_lds[1][qt * 16 + lg * 4 + r][kt * 16 + li] = f2bf(e2);
                }
            }
        }

        // V fragments (shared by both states and both q tiles)
        const unsigned short* vp = vbase + kv;
        short8 vf[4];
        #pragma unroll
        for (int dt = 0; dt < 4; dt++)
            vf[dt] = *(const short8*)(vp + (size_t)dt * 16 * TSEQ);

        #pragma unroll
        for (int qt = 0; qt < 2; qt++) {
            short8 pa1 = *(const short8*)&p_lds[0][qt * 16 + li][lg * 8];
            short8 pa2 = *(const short8*)&p_lds[1][qt * 16 + li][lg * 8];
            #pragma unroll
            for (int dt = 0; dt < 4; dt++) {
                acc1[qt][dt] = __builtin_amdgcn_mfma_f32_16x16x32_bf16(pa1, vf[dt], acc1[qt][dt], 0, 0, 0);
                acc2[qt][dt] = __builtin_amdgcn_mfma_f32_16x16x32_bf16(pa2, vf[dt], acc2[qt][dt], 0, 0, 0);
            }
        }
    }

    // reduce row sums across the 16 lanes of each li-group
    #pragma unroll
    for (int qt = 0; qt < 2; qt++)
        #pragma unroll
        for (int r = 0; r < 4; r++) {
            #pragma unroll
            for (int m = 1; m < 16; m <<= 1) {
                ls1[qt][r] += __shfl_xor(ls1[qt][r], m, 64);
                ls2[qt][r] += __shfl_xor(ls2[qt][r], m, 64);
            }
        }

    float hw[4], hb[4];
    #pragma unroll
    for (int t = 0; t < 4; t++) { hw[t] = hn_w[t * 16 + li]; hb[t] = hn_b[t * 16 + li]; }

    const int b = bh >> 2, h = bh & 3;
    #pragma unroll
    for (int qt = 0; qt < 2; qt++) {
        #pragma unroll
        for (int r = 0; r < 4; r++) {
            float il1 = 1.f / ls1[qt][r];
            float il2 = lam / ls2[qt][r];
            float o[4];
            float s = 0.f, sq = 0.f;
            #pragma unroll
            for (int t = 0; t < 4; t++) {
                o[t] = acc1[qt][t][r] * il1 - acc2[qt][t][r] * il2;
                s += o[t]; sq += o[t] * o[t];
            }
            #pragma unroll
            for (int m = 1; m < 16; m <<= 1) { s += __shfl_xor(s, m, 64); sq += __shfl_xor(sq, m, 64); }
            float mean = s * (1.f / 64.f);
            float var  = sq * (1.f / 64.f) - mean * mean;
            float rstd = rsqrtf(var + LN_EPS);
            int qrow = qw + qt * 16 + lg * 4 + r;
            unsigned short* op = attn_out + ((size_t)b * TSEQ + qrow) * 256 + h * 64;
            #pragma unroll
            for (int t = 0; t < 4; t++) {
                op[t * 16 + li] = f2bf(((o[t] - mean) * rstd * hw[t] + hb[t]) * 0.2f);
            }
        }
    }
}

// ---------------- Kernel C: output projection + residual (MFMA) --------
__global__ __launch_bounds__(256) void k_out(
    const unsigned short* __restrict__ attn_out, const unsigned short* __restrict__ WoT,
    const float* __restrict__ tokens, float* __restrict__ out)
{
    const int tid = threadIdx.x;
    const int w = tid >> 6, lane = tid & 63;
    const int lg = lane >> 4, li = lane & 15;
    const int rt = w >> 1, chh = w & 1;
    const int r0 = blockIdx.x * 32 + rt * 16;

    short8 a[8];
    const unsigned short* ap = attn_out + (size_t)(r0 + li) * 256 + lg * 8;
    #pragma unroll
    for (int kc = 0; kc < 8; kc++) a[kc] = *(const short8*)(ap + kc * 32);

    #pragma unroll
    for (int c2 = 0; c2 < 4; c2++) {
        int ct = chh * 4 + c2;
        f32x4 acc = {};
        const unsigned short* bp = WoT + (size_t)(ct * 16 + li) * 256 + lg * 8;
        #pragma unroll
        for (int kc = 0; kc < 8; kc++) {
            short8 bf = *(const short8*)(bp + kc * 32);
            acc = __builtin_amdgcn_mfma_f32_16x16x32_bf16(a[kc], bf, acc, 0, 0, 0);
        }
        #pragma unroll
        for (int r = 0; r < 4; r++) {
            size_t idx = (size_t)(r0 + lg * 4 + r) * 128 + ct * 16 + li;
            out[idx] = tokens[idx] + acc[r];
        }
    }
}

extern "C" void kernel_launch(void* const* d_in, const int* in_sizes, int n_in,
                              void* d_out, int out_size, void* d_ws, size_t ws_size,
                              hipStream_t stream) {
    const float* tokens = (const float*)d_in[0];
    const float* ln_w   = (const float*)d_in[1];
    const float* ln_b   = (const float*)d_in[2];
    const float* wq     = (const float*)d_in[3];
    const float* wk     = (const float*)d_in[4];
    const float* wv     = (const float*)d_in[5];
    const float* wo     = (const float*)d_in[6];
    const float* lq1    = (const float*)d_in[7];
    const float* lk1    = (const float*)d_in[8];
    const float* lq2    = (const float*)d_in[9];
    const float* lk2    = (const float*)d_in[10];
    const float* sigs   = (const float*)d_in[11];
    const float* sign   = (const float*)d_in[12];
    const float* hn_w   = (const float*)d_in[13];
    const float* hn_b   = (const float*)d_in[14];

    const size_t n_qk = (size_t)BH * TSEQ * 64;   // 4.19M
    unsigned short* Qg      = (unsigned short*)d_ws;
    unsigned short* Kg      = Qg + n_qk;
    unsigned short* Vtg     = Kg + n_qk;
    unsigned short* attn_o  = Vtg + n_qk;         // [16384][256] bf16
    unsigned short* WqkvT   = attn_o + n_qk;      // [768][128]
    unsigned short* WoT     = WqkvT + 768 * 128;  // [128][256]

    k_prep<<<dim3(32), dim3(256), 0, stream>>>(wq, wk, wv, wo, WqkvT, WoT);
    k_qkv<<<dim3(BATCH * TSEQ / 32), dim3(256), 0, stream>>>(
        tokens, ln_w, ln_b, WqkvT, Qg, Kg, Vtg);
    k_attn<<<dim3(2048), dim3(64), 0, stream>>>(
        Qg, Kg, Vtg, lq1, lk1, lq2, lk2, sigs, sign, hn_w, hn_b, attn_o);
    k_out<<<dim3(BATCH * TSEQ / 32), dim3(256), 0, stream>>>(
        attn_o, WoT, tokens, (float*)d_out);
}

// Round 5
// 65.338 us; speedup vs baseline: 3.2365x; 1.1329x over previous
//
#include <hip/hip_runtime.h>
#include <hip/hip_bf16.h>

#define TSEQ 2048
#define BATCH 8
#define NHEAD 4
#define BH (BATCH*NHEAD)
#define HD 32
#define SCALE 0.17677669529663687f   /* 1/sqrt(32) */
#define LAMBDA_INIT 0.8f
#define LN_EPS 1e-5f

typedef __attribute__((ext_vector_type(8))) short short8;
typedef __attribute__((ext_vector_type(4))) float f32x4;

static __device__ __forceinline__ unsigned short f2bf(float x) {
    unsigned int u = __float_as_uint(x);
    unsigned int r = (u + 0x7fffu + ((u >> 16) & 1u)) >> 16;
    return (unsigned short)r;
}

// ---------------- Kernel P: weight transpose + bf16 cast ----------------
__global__ __launch_bounds__(256) void k_prep(
    const float* __restrict__ wq, const float* __restrict__ wk,
    const float* __restrict__ wv, const float* __restrict__ wo,
    unsigned short* __restrict__ WqkvT, unsigned short* __restrict__ WoT)
{
    __shared__ float xt[64][65];
    const int bid = blockIdx.x, tid = threadIdx.x;
    const float* src; int srcN, k0, nsrc0, dstK;
    unsigned short* dst;
    if (bid < 24) {
        int ntile = bid >> 1, ktile = bid & 1;
        int gn0 = ntile * 64; k0 = ktile * 64;
        int mat = gn0 >> 8;
        src = (mat == 0) ? wq : (mat == 1 ? wk : wv);
        srcN = 256; nsrc0 = gn0 & 255;
        dst = WqkvT + (size_t)gn0 * 128; dstK = 128;
    } else {
        int b2 = bid - 24;
        int ntile = b2 >> 2, ktile = b2 & 3;
        int gn0 = ntile * 64; k0 = ktile * 64;
        src = wo; srcN = 128; nsrc0 = gn0;
        dst = WoT + (size_t)gn0 * 256; dstK = 256;
    }
    {
        int r = tid >> 2, cs = tid & 3;
        const float* sp = src + (size_t)(k0 + r) * srcN + nsrc0 + cs * 16;
        #pragma unroll
        for (int j = 0; j < 4; j++) {
            float4 v = *(const float4*)(sp + j * 4);
            xt[r][cs * 16 + j * 4 + 0] = v.x;
            xt[r][cs * 16 + j * 4 + 1] = v.y;
            xt[r][cs * 16 + j * 4 + 2] = v.z;
            xt[r][cs * 16 + j * 4 + 3] = v.w;
        }
    }
    __syncthreads();
    {
        int n = tid >> 2, ks = tid & 3;
        short8 o0, o1;
        #pragma unroll
        for (int j = 0; j < 8; j++) {
            o0[j] = (short)f2bf(xt[ks * 16 + j][n]);
            o1[j] = (short)f2bf(xt[ks * 16 + 8 + j][n]);
        }
        unsigned short* dp = dst + (size_t)n * dstK + k0 + ks * 16;
        *(short8*)dp = o0;
        *(short8*)(dp + 8) = o1;
    }
}

// ---------------- Kernel A: LayerNorm + QKV projection (MFMA) ----------
__global__ __launch_bounds__(256) void k_qkv(
    const float* __restrict__ tokens, const float* __restrict__ ln_w,
    const float* __restrict__ ln_b, const unsigned short* __restrict__ WqkvT,
    unsigned short* __restrict__ Qg, unsigned short* __restrict__ Kg,
    unsigned short* __restrict__ Vtg)
{
    __shared__ unsigned short x_lds[32][132];
    __shared__ unsigned short c_lds[4][16][68];
    const int tid = threadIdx.x;
    const int r0 = blockIdx.x * 32;

    {
        int row = tid >> 3, sub = tid & 7;
        const float* tr = tokens + (size_t)(r0 + row) * 128 + sub * 16;
        float v[16]; float s = 0.f, sq = 0.f;
        #pragma unroll
        for (int j = 0; j < 16; j += 4) {
            float4 t4 = *(const float4*)(tr + j);
            v[j] = t4.x; v[j + 1] = t4.y; v[j + 2] = t4.z; v[j + 3] = t4.w;
        }
        #pragma unroll
        for (int j = 0; j < 16; j++) { s += v[j]; sq += v[j] * v[j]; }
        #pragma unroll
        for (int m = 1; m < 8; m <<= 1) { s += __shfl_xor(s, m, 64); sq += __shfl_xor(sq, m, 64); }
        float mean = s * (1.f / 128.f);
        float var  = sq * (1.f / 128.f) - mean * mean;
        float rstd = rsqrtf(var + LN_EPS);
        short8 o0, o1;
        #pragma unroll
        for (int j = 0; j < 8; j++) {
            int c0 = sub * 16 + j, c1 = sub * 16 + 8 + j;
            o0[j] = (short)f2bf((v[j] - mean) * rstd * ln_w[c0] + ln_b[c0]);
            o1[j] = (short)f2bf((v[8 + j] - mean) * rstd * ln_w[c1] + ln_b[c1]);
        }
        *(short8*)&x_lds[row][sub * 16] = o0;
        *(short8*)&x_lds[row][sub * 16 + 8] = o1;
    }
    __syncthreads();

    const int w = tid >> 6, lane = tid & 63;
    const int lg = lane >> 4, li = lane & 15;
    const int rt = w >> 1, ch = w & 1;

    short8 a[4];
    #pragma unroll
    for (int kc = 0; kc < 4; kc++)
        a[kc] = *(const short8*)&x_lds[rt * 16 + li][kc * 32 + lg * 8];

    const int b   = r0 >> 11;
    const int tw0 = (r0 & 2047) + rt * 16;

    #pragma unroll
    for (int cc = 0; cc < 6; cc++) {
        f32x4 acc[4] = {};
        #pragma unroll
        for (int t = 0; t < 4; t++) {
            int n0 = ch * 384 + cc * 64 + t * 16;
            const unsigned short* bp = WqkvT + (size_t)(n0 + li) * 128 + lg * 8;
            #pragma unroll
            for (int kc = 0; kc < 4; kc++) {
                short8 bf = *(const short8*)(bp + kc * 32);
                acc[t] = __builtin_amdgcn_mfma_f32_16x16x32_bf16(a[kc], bf, acc[t], 0, 0, 0);
            }
        }
        #pragma unroll
        for (int t = 0; t < 4; t++)
            #pragma unroll
            for (int r = 0; r < 4; r++)
                c_lds[w][lg * 4 + r][t * 16 + li] = f2bf(acc[t][r]);

        int gc = ch * 6 + cc;
        int kind = gc >> 2, h = gc & 3;
        size_t bhh = (size_t)(b * NHEAD + h);
        if (kind < 2) {
            unsigned short* base = (kind == 0) ? Qg : Kg;
            int row = lane >> 2, seg = lane & 3;
            unsigned short* dp = base + (bhh * TSEQ + tw0 + row) * 64 + seg * 16;
            *(short8*)dp       = *(const short8*)&c_lds[w][row][seg * 16];
            *(short8*)(dp + 8) = *(const short8*)&c_lds[w][row][seg * 16 + 8];
        } else {
            int d = lane;
            short8 v0, v1;
            #pragma unroll
            for (int j = 0; j < 8; j++) {
                v0[j] = (short)c_lds[w][j][d];
                v1[j] = (short)c_lds[w][8 + j][d];
            }
            unsigned short* dp = Vtg + (bhh * 64 + d) * TSEQ + tw0;
            *(short8*)dp = v0;
            *(short8*)(dp + 8) = v1;
        }
    }
}

// ---- Kernel B: fused banded differential attention + wo projection ----
// 256 threads. Wave w = head h for 32 q rows of batch b; attention result
// (head-LN'd, *0.2, bf16) goes to LDS ao[32][256]; then all 4 waves do the
// 32x256x128 wo GEMM with fused residual. XCD mapping: b = bid&7 keeps one
// batch's K/V (2 MB) inside one XCD's 4 MB L2.
__global__ __launch_bounds__(256) void k_attn2(
    const unsigned short* __restrict__ Qg, const unsigned short* __restrict__ Kg,
    const unsigned short* __restrict__ Vtg,
    const float* __restrict__ lq1, const float* __restrict__ lk1,
    const float* __restrict__ lq2, const float* __restrict__ lk2,
    const float* __restrict__ sig_s_p, const float* __restrict__ sig_n_p,
    const float* __restrict__ hn_w, const float* __restrict__ hn_b,
    const unsigned short* __restrict__ WoT, const float* __restrict__ tokens,
    float* __restrict__ out)
{
    __shared__ unsigned short p_lds[4][2][32][36];
    __shared__ unsigned short ao[32][264];

    const int tid  = threadIdx.x;
    const int w    = tid >> 6;        // wave = head
    const int lane = tid & 63;
    const int lg   = lane >> 4;
    const int li   = lane & 15;

    const int b  = blockIdx.x & 7;    // XCD-aware: batch pinned to XCD
    const int qw = (blockIdx.x >> 3) * 32;
    const int bh = b * NHEAD + w;

    float d1 = 0.f, d2 = 0.f;
    for (int i = 0; i < HD; i++) { d1 += lq1[i] * lk1[i]; d2 += lq2[i] * lk2[i]; }
    const float lam = __expf(d1) - __expf(d2) + LAMBDA_INIT;
    const float ss = fmaxf(sig_s_p[0], 1.f);
    const float sn = fmaxf(sig_n_p[0], 1.f);
    const float c1 = -0.5f / (ss * ss);
    const float c2 = -0.5f / (sn * sn);

    int W = (int)ceilf(fmaxf(ss, sn) * 8.f);
    W = (W + 31) & ~31;
    if (W < 64) W = 64;
    int lo = qw - W; if (lo < 0) lo = 0; lo &= ~31;
    int hi = qw + 32 + W; hi = (hi + 31) & ~31; if (hi > TSEQ) hi = TSEQ;

    short8 q1[2], q2[2];
    #pragma unroll
    for (int qt = 0; qt < 2; qt++) {
        const unsigned short* qp = Qg + ((size_t)bh * TSEQ + (qw + qt * 16 + li)) * 64;
        q1[qt] = *(const short8*)(qp + lg * 8);
        q2[qt] = *(const short8*)(qp + 32 + lg * 8);
    }

    const unsigned short* kbase = Kg  + ((size_t)bh * TSEQ + li) * 64 + lg * 8;
    const unsigned short* vbase = Vtg + ((size_t)bh * 64 + li) * TSEQ + lg * 8;

    f32x4 acc1[2][4] = {}, acc2[2][4] = {};
    float ls1[2][4] = {}, ls2[2][4] = {};
    const f32x4 zero4 = {0.f, 0.f, 0.f, 0.f};

    for (int kv = lo; kv < hi; kv += 32) {
        const unsigned short* kp = kbase + (size_t)kv * 64;
        short8 kf1[2], kf2[2];
        kf1[0] = *(const short8*)(kp);
        kf2[0] = *(const short8*)(kp + 32);
        kf1[1] = *(const short8*)(kp + 1024);
        kf2[1] = *(const short8*)(kp + 1024 + 32);

        #pragma unroll
        for (int qt = 0; qt < 2; qt++) {
            f32x4 s1[2], s2[2];
            #pragma unroll
            for (int kt = 0; kt < 2; kt++) {
                s1[kt] = __builtin_amdgcn_mfma_f32_16x16x32_bf16(q1[qt], kf1[kt], zero4, 0, 0, 0);
                s2[kt] = __builtin_amdgcn_mfma_f32_16x16x32_bf16(q2[qt], kf2[kt], zero4, 0, 0, 0);
            }
            const float rb = (float)(kv + li - qw - qt * 16 - 4 * lg);
            #pragma unroll
            for (int kt = 0; kt < 2; kt++) {
                #pragma unroll
                for (int r = 0; r < 4; r++) {
                    float rel = rb + (float)(16 * kt - r);
                    float rr  = rel * rel;
                    float e1  = __expf(fmaf(s1[kt][r], SCALE, c1 * rr));
                    float e2  = __expf(fmaf(s2[kt][r], SCALE, c2 * rr));
                    ls1[qt][r] += e1;
                    ls2[qt][r] += e2;
                    p_lds[w][0][qt * 16 + lg * 4 + r][kt * 16 + li] = f2bf(e1);
                    p_lds[w][1][qt * 16 + lg * 4 + r][kt * 16 + li] = f2bf(e2);
                }
            }
        }

        const unsigned short* vp = vbase + kv;
        short8 vf[4];
        #pragma unroll
        for (int dt = 0; dt < 4; dt++)
            vf[dt] = *(const short8*)(vp + (size_t)dt * 16 * TSEQ);

        #pragma unroll
        for (int qt = 0; qt < 2; qt++) {
            short8 pa1 = *(const short8*)&p_lds[w][0][qt * 16 + li][lg * 8];
            short8 pa2 = *(const short8*)&p_lds[w][1][qt * 16 + li][lg * 8];
            #pragma unroll
            for (int dt = 0; dt < 4; dt++) {
                acc1[qt][dt] = __builtin_amdgcn_mfma_f32_16x16x32_bf16(pa1, vf[dt], acc1[qt][dt], 0, 0, 0);
                acc2[qt][dt] = __builtin_amdgcn_mfma_f32_16x16x32_bf16(pa2, vf[dt], acc2[qt][dt], 0, 0, 0);
            }
        }
    }

    #pragma unroll
    for (int qt = 0; qt < 2; qt++)
        #pragma unroll
        for (int r = 0; r < 4; r++) {
            #pragma unroll
            for (int m = 1; m < 16; m <<= 1) {
                ls1[qt][r] += __shfl_xor(ls1[qt][r], m, 64);
                ls2[qt][r] += __shfl_xor(ls2[qt][r], m, 64);
            }
        }

    {
        float hw[4], hb[4];
        #pragma unroll
        for (int t = 0; t < 4; t++) { hw[t] = hn_w[t * 16 + li]; hb[t] = hn_b[t * 16 + li]; }

        #pragma unroll
        for (int qt = 0; qt < 2; qt++) {
            #pragma unroll
            for (int r = 0; r < 4; r++) {
                float il1 = 1.f / ls1[qt][r];
                float il2 = lam / ls2[qt][r];
                float o[4];
                float s = 0.f, sq = 0.f;
                #pragma unroll
                for (int t = 0; t < 4; t++) {
                    o[t] = acc1[qt][t][r] * il1 - acc2[qt][t][r] * il2;
                    s += o[t]; sq += o[t] * o[t];
                }
                #pragma unroll
                for (int m = 1; m < 16; m <<= 1) { s += __shfl_xor(s, m, 64); sq += __shfl_xor(sq, m, 64); }
                float mean = s * (1.f / 64.f);
                float var  = sq * (1.f / 64.f) - mean * mean;
                float rstd = rsqrtf(var + LN_EPS);
                int arow = qt * 16 + lg * 4 + r;
                #pragma unroll
                for (int t = 0; t < 4; t++) {
                    ao[arow][w * 64 + t * 16 + li] =
                        f2bf(((o[t] - mean) * rstd * hw[t] + hb[t]) * 0.2f);
                }
            }
        }
    }
    __syncthreads();

    // ---- wo GEMM: 32 rows x 256 k x 128 cols; wave w does cols [w*32, w*32+32)
    const int row0 = b * TSEQ + qw;
    #pragma unroll
    for (int c2 = 0; c2 < 2; c2++) {
        const int ct = w * 2 + c2;
        short8 bfr[8];
        const unsigned short* bp = WoT + (size_t)(ct * 16 + li) * 256 + lg * 8;
        #pragma unroll
        for (int kc = 0; kc < 8; kc++) bfr[kc] = *(const short8*)(bp + kc * 32);

        #pragma unroll
        for (int qt = 0; qt < 2; qt++) {
            f32x4 acc = {};
            #pragma unroll
            for (int kc = 0; kc < 8; kc++) {
                short8 af = *(const short8*)&ao[qt * 16 + li][kc * 32 + lg * 8];
                acc = __builtin_amdgcn_mfma_f32_16x16x32_bf16(af, bfr[kc], acc, 0, 0, 0);
            }
            #pragma unroll
            for (int r = 0; r < 4; r++) {
                size_t idx = (size_t)(row0 + qt * 16 + lg * 4 + r) * 128 + ct * 16 + li;
                out[idx] = tokens[idx] + acc[r];
            }
        }
    }
}

extern "C" void kernel_launch(void* const* d_in, const int* in_sizes, int n_in,
                              void* d_out, int out_size, void* d_ws, size_t ws_size,
                              hipStream_t stream) {
    const float* tokens = (const float*)d_in[0];
    const float* ln_w   = (const float*)d_in[1];
    const float* ln_b   = (const float*)d_in[2];
    const float* wq     = (const float*)d_in[3];
    const float* wk     = (const float*)d_in[4];
    const float* wv     = (const float*)d_in[5];
    const float* wo     = (const float*)d_in[6];
    const float* lq1    = (const float*)d_in[7];
    const float* lk1    = (const float*)d_in[8];
    const float* lq2    = (const float*)d_in[9];
    const float* lk2    = (const float*)d_in[10];
    const float* sigs   = (const float*)d_in[11];
    const float* sign   = (const float*)d_in[12];
    const float* hn_w   = (const float*)d_in[13];
    const float* hn_b   = (const float*)d_in[14];

    const size_t n_qk = (size_t)BH * TSEQ * 64;   // 4.19M
    unsigned short* Qg      = (unsigned short*)d_ws;
    unsigned short* Kg      = Qg + n_qk;
    unsigned short* Vtg     = Kg + n_qk;
    unsigned short* WqkvT   = Vtg + n_qk;         // [768][128]
    unsigned short* WoT     = WqkvT + 768 * 128;  // [128][256]

    k_prep<<<dim3(32), dim3(256), 0, stream>>>(wq, wk, wv, wo, WqkvT, WoT);
    k_qkv<<<dim3(BATCH * TSEQ / 32), dim3(256), 0, stream>>>(
        tokens, ln_w, ln_b, WqkvT, Qg, Kg, Vtg);
    k_attn2<<<dim3(512), dim3(256), 0, stream>>>(
        Qg, Kg, Vtg, lq1, lk1, lq2, lk2, sigs, sign, hn_w, hn_b,
        WoT, tokens, (float*)d_out);
}